// Round 1
// 220.322 us; speedup vs baseline: 1.0628x; 1.0628x over previous
//
#include <hip/hip_runtime.h>
#include <hip/hip_bf16.h>
#include <math.h>

#define N_NODES 20000
#define N_EDGES 320000
#define ET (N_EDGES + N_NODES)   // with self loops = 340000
#define IN_C 512
#define HEADS 8
#define HID 32
#define HH (HEADS * HID)         // 256
#define OUT_C 40
#define NEG_SLOPE 0.2f

typedef __attribute__((ext_vector_type(8))) short short8;
typedef __attribute__((ext_vector_type(4))) float floatx4;

static __device__ __forceinline__ unsigned short f2bf(float f) {
  __hip_bfloat16 h = __float2bfloat16(f);
  return *(unsigned short*)&h;
}
static __device__ __forceinline__ float bf2f_lo(unsigned int u) {
  return __uint_as_float(u << 16);
}
static __device__ __forceinline__ float bf2f_hi(unsigned int u) {
  return __uint_as_float(u & 0xFFFF0000u);
}

// ================= L1: w1/w2 -> bf16 (w2 transposed)  +  edge count ==========
#define WCONV_BLOCKS (IN_C * HH / 256)          // 512
#define W2CONV_BLOCKS (HH * OUT_C / 256)        // 40
#define COUNT_BLOCKS ((ET + 255) / 256)         // 1329
__global__ __launch_bounds__(256) void prep_kernel(
    const float* __restrict__ w1, const float* __restrict__ w2,
    const int* __restrict__ ei, unsigned short* __restrict__ wbT,
    unsigned short* __restrict__ w2bT, int* __restrict__ deg) {
  if (blockIdx.x < WCONV_BLOCKS) {
    int j = blockIdx.x * 256 + threadIdx.x;     // coalesced read of w1
    int k = j >> 8, n = j & 255;
    wbT[(size_t)n * IN_C + k] = f2bf(w1[j]);
  } else if (blockIdx.x < WCONV_BLOCKS + W2CONV_BLOCKS) {
    int j = (blockIdx.x - WCONV_BLOCKS) * 256 + threadIdx.x;  // 10240
    int k = j / OUT_C, oc = j % OUT_C;
    w2bT[oc * HH + k] = f2bf(w2[j]);
  } else {
    int e = (blockIdx.x - WCONV_BLOCKS - W2CONV_BLOCKS) * 256 + threadIdx.x;
    if (e < ET) {
      int dst = (e < N_EDGES) ? ei[N_EDGES + e] : (e - N_EDGES);
      atomicAdd(&deg[dst], 1);
    }
  }
}

// ================= L2: GEMM1 (MFMA bf16, f32 A staged+converted) + CSR scan ==
#define BM 64
#define BN 128
#define BK 32
#define APAD 40   // row stride in shorts (80B)
#define GY ((N_NODES + BM - 1) / BM)            // 313
#define GEMM_BLOCKS (2 * GY)                    // 626
__global__ __launch_bounds__(256) void gemm1_kernel(
    const float* __restrict__ X, const unsigned short* __restrict__ BT,
    const float* __restrict__ bias, unsigned short* __restrict__ C,
    const int* __restrict__ deg, int* __restrict__ offs, int* __restrict__ cursor) {
  if (blockIdx.x >= GEMM_BLOCKS) {
    // ---- CSR exclusive scan: 250 threads x 80 nodes, register-buffered ----
    __shared__ int wsum[4];
    int t = threadIdx.x;
    int4 buf[20];
    int s = 0;
    if (t < 250) {
      const int4* dp = (const int4*)deg + t * 20;
#pragma unroll
      for (int i = 0; i < 20; i++) {
        buf[i] = dp[i];                      // independent loads — pipelined
        s += buf[i].x + buf[i].y + buf[i].z + buf[i].w;
      }
    }
    int lane = t & 63, w = t >> 6;
    int inc = s;
    for (int o = 1; o < 64; o <<= 1) {
      int u = __shfl_up(inc, o, 64);
      if (lane >= o) inc += u;
    }
    if (lane == 63) wsum[w] = inc;
    __syncthreads();
    int waveOff = 0;
    for (int i = 0; i < w; i++) waveOff += wsum[i];
    int running = waveOff + inc - s;         // exclusive thread offset
    if (t < 250) {
      int base = t * 80;
#pragma unroll
      for (int i = 0; i < 20; i++) {
        int4 v = buf[i];
        int4 o;
        o.x = running;
        o.y = o.x + v.x;
        o.z = o.y + v.y;
        o.w = o.z + v.z;
        running = o.w + v.w;
        *(int4*)(offs + base + i * 4) = o;
        *(int4*)(cursor + base + i * 4) = o;
      }
    }
    if (t == 0) offs[N_NODES] = ET;
    return;
  }
  // ---- GEMM tile ----
  __shared__ unsigned short As[BM][APAD];   // [64][40]
  __shared__ unsigned short Bs[BN][APAD];   // [128][40]
  const int tid = threadIdx.x;
  const int lane = tid & 63, wave = tid >> 6;
  const int wm = (wave & 1) * 32;
  const int wn = (wave >> 1) * 64;
  const int r16 = lane & 15, q = lane >> 4;
  const int bx = blockIdx.x & 1, by = blockIdx.x >> 1;
  const int rowBase = by * BM;
  const int colBase = bx * BN;
  floatx4 acc[2][4] = {};

  for (int k0 = 0; k0 < IN_C; k0 += BK) {
    {
      int row = tid >> 2, kc = (tid & 3) * 8;
      int arow = rowBase + row;
      float4 v0 = make_float4(0.f, 0.f, 0.f, 0.f), v1 = v0;
      if (arow < N_NODES) {
        const float* p = X + (size_t)arow * IN_C + k0 + kc;
        v0 = *(const float4*)p;
        v1 = *(const float4*)(p + 4);
      }
      unsigned short tmp[8] = {f2bf(v0.x), f2bf(v0.y), f2bf(v0.z), f2bf(v0.w),
                               f2bf(v1.x), f2bf(v1.y), f2bf(v1.z), f2bf(v1.w)};
      *(float4*)&As[row][kc] = *(const float4*)tmp;
    }
#pragma unroll
    for (int i = 0; i < 2; i++) {
      int c = tid + i * 256;
      int row = c >> 2, kc = (c & 3) * 8;
      float4 v = *(const float4*)(BT + (size_t)(colBase + row) * IN_C + k0 + kc);
      *(float4*)&Bs[row][kc] = v;
    }
    __syncthreads();
    short8 afrag[2], bfrag[4];
#pragma unroll
    for (int mt = 0; mt < 2; mt++)
      afrag[mt] = *(const short8*)&As[wm + mt * 16 + r16][q * 8];
#pragma unroll
    for (int nt = 0; nt < 4; nt++)
      bfrag[nt] = *(const short8*)&Bs[wn + nt * 16 + r16][q * 8];
#pragma unroll
    for (int mt = 0; mt < 2; mt++)
#pragma unroll
      for (int nt = 0; nt < 4; nt++)
        acc[mt][nt] = __builtin_amdgcn_mfma_f32_16x16x32_bf16(
            afrag[mt], bfrag[nt], acc[mt][nt], 0, 0, 0);
    __syncthreads();
  }
#pragma unroll
  for (int mt = 0; mt < 2; mt++) {
#pragma unroll
    for (int nt = 0; nt < 4; nt++) {
      int col = colBase + wn + nt * 16 + r16;
      float bb = bias[col];
#pragma unroll
      for (int r = 0; r < 4; r++) {
        int row = rowBase + wm + mt * 16 + q * 4 + r;
        if (row < N_NODES) C[(size_t)row * HH + col] = f2bf(acc[mt][nt][r] + bb);
      }
    }
  }
}

// ================= L3: CSR fill + attn1 (wave-per-node dots) =================
#define FILL_BLOCKS ((ET + 255) / 256)          // 1329
#define ATTN1_BLOCKS (N_NODES / 4)              // 5000
__global__ __launch_bounds__(256) void fill_attn1_kernel(
    const int* __restrict__ ei, int* __restrict__ cursor, int* __restrict__ csr,
    const unsigned short* __restrict__ h1b, const float* __restrict__ asrc,
    const float* __restrict__ adst, float* __restrict__ as1, float* __restrict__ ad1) {
  if (blockIdx.x < FILL_BLOCKS) {
    int e = blockIdx.x * 256 + threadIdx.x;
    if (e >= ET) return;
    int src, dst;
    if (e < N_EDGES) { src = ei[e]; dst = ei[N_EDGES + e]; }
    else { src = e - N_EDGES; dst = src; }
    int pos = atomicAdd(&cursor[dst], 1);
    csr[pos] = src;
  } else {
    int wave = threadIdx.x >> 6, lane = threadIdx.x & 63;
    int n = (blockIdx.x - FILL_BLOCKS) * 4 + wave;   // exact: 5000*4 = 20000
    int c4 = lane * 4;
    uint2 raw = *(const uint2*)(h1b + (size_t)n * HH + c4);
    float h0 = bf2f_lo(raw.x), h1 = bf2f_hi(raw.x);
    float h2 = bf2f_lo(raw.y), h3 = bf2f_hi(raw.y);
    float4 sa = *(const float4*)(asrc + c4);
    float4 sd = *(const float4*)(adst + c4);
    float ps = h0 * sa.x + h1 * sa.y + h2 * sa.z + h3 * sa.w;
    float pd = h0 * sd.x + h1 * sd.y + h2 * sd.z + h3 * sd.w;
#pragma unroll
    for (int o = 4; o > 0; o >>= 1) {
      ps += __shfl_down(ps, o, 8);
      pd += __shfl_down(pd, o, 8);
    }
    if ((lane & 7) == 0) {
      as1[n * HEADS + (lane >> 3)] = ps;
      ad1[n * HEADS + (lane >> 3)] = pd;
    }
  }
}

// ================= L4: fused agg1 + GEMM2(MFMA) + attn2 ======================
// Block = 16 nodes, 4 waves. Phase A: 2 edge streams per wave, 32 lanes/edge,
// each lane loads ONE contiguous 16B chunk (8 channels) -> every vmem instr
// covers whole cachelines (8 full 64B lines per 512B row vs 16 half-consumed
// touches in the 16-lane layout). 1-deep software pipeline on the gather.
// Streams combined via shfl_xor(32). ELU epilogue split across half-waves and
// uses __expf(x)-1 (bf16-quantized anyway). w2 B-fragments loaded in Phase B
// so 32 VGPRs are not held live through the gather.
#define NPB 16
#define H2ROW 264
__global__ __launch_bounds__(256) void layer1_fused_kernel(
    const unsigned short* __restrict__ h1b, const float* __restrict__ as1,
    const float* __restrict__ ad1, const int* __restrict__ offs,
    const int* __restrict__ csr, const float* __restrict__ b1,
    const unsigned short* __restrict__ w2bT, const float* __restrict__ b2,
    const float* __restrict__ asrc2, const float* __restrict__ adst2,
    float* __restrict__ h3, float* __restrict__ as2, float* __restrict__ ad2) {
  __shared__ __align__(16) unsigned short h2s[NPB][H2ROW];  // 8448 B
  __shared__ float psum[3][NPB], pdsum[3][NPB];
  const int tid = threadIdx.x;
  const int wave = tid >> 6, lane = tid & 63;
  const int r16 = lane & 15, q = lane >> 4;
  const int nodeBase = blockIdx.x * NPB;

  // ---- Phase A: gather, 2 streams x 32 lanes, 8 contiguous channels/lane ----
  const int strm = lane >> 5;          // 0..1: edge stream
  const int l32 = lane & 31;
  const int c8 = l32 * 8;              // channel base (16 B)
  const int head = l32 >> 2;           // 8 channels sit inside one 32-ch head
  float4 bb = *(const float4*)(b1 + c8 + strm * 4);   // this lane's 4 out chans
  for (int i = 0; i < 4; i++) {
    int local = wave * 4 + i;
    int n = nodeBase + local;
    int beg = offs[n], end = offs[n + 1];
    float ad = ad1[n * HEADS + head];
    float acc[8] = {};
    float l = 0.f;
    int k = beg + strm;
    if (k < end) {
      int src = csr[k];
      uint4 r = *(const uint4*)(h1b + ((unsigned)src << 8) + c8);
      float e = as1[src * HEADS + head];
      for (k += 2; k < end; k += 2) {
        // issue next edge's loads before consuming current (1-deep pipeline)
        int src2 = csr[k];
        uint4 r2 = *(const uint4*)(h1b + ((unsigned)src2 << 8) + c8);
        float e2 = as1[src2 * HEADS + head];
        float t = e + ad;
        t = (t > 0.f) ? t : NEG_SLOPE * t;
        float p = __expf(t);
        l += p;
        acc[0] = fmaf(p, bf2f_lo(r.x), acc[0]);
        acc[1] = fmaf(p, bf2f_hi(r.x), acc[1]);
        acc[2] = fmaf(p, bf2f_lo(r.y), acc[2]);
        acc[3] = fmaf(p, bf2f_hi(r.y), acc[3]);
        acc[4] = fmaf(p, bf2f_lo(r.z), acc[4]);
        acc[5] = fmaf(p, bf2f_hi(r.z), acc[5]);
        acc[6] = fmaf(p, bf2f_lo(r.w), acc[6]);
        acc[7] = fmaf(p, bf2f_hi(r.w), acc[7]);
        r = r2; e = e2;
      }
      float t = e + ad;
      t = (t > 0.f) ? t : NEG_SLOPE * t;
      float p = __expf(t);
      l += p;
      acc[0] = fmaf(p, bf2f_lo(r.x), acc[0]);
      acc[1] = fmaf(p, bf2f_hi(r.x), acc[1]);
      acc[2] = fmaf(p, bf2f_lo(r.y), acc[2]);
      acc[3] = fmaf(p, bf2f_hi(r.y), acc[3]);
      acc[4] = fmaf(p, bf2f_lo(r.z), acc[4]);
      acc[5] = fmaf(p, bf2f_hi(r.z), acc[5]);
      acc[6] = fmaf(p, bf2f_lo(r.w), acc[6]);
      acc[7] = fmaf(p, bf2f_hi(r.w), acc[7]);
    }
    // combine the two streams (butterfly -> both halves hold totals)
#pragma unroll
    for (int j = 0; j < 8; j++) acc[j] += __shfl_xor(acc[j], 32, 64);
    l += __shfl_xor(l, 32, 64);
    float li = 1.f / (l + 1e-16f);
    // each half-wave finalizes 4 of this lane's 8 channels
    float v0 = (strm ? acc[4] : acc[0]) * li + bb.x;
    float v1 = (strm ? acc[5] : acc[1]) * li + bb.y;
    float v2 = (strm ? acc[6] : acc[2]) * li + bb.z;
    float v3 = (strm ? acc[7] : acc[3]) * li + bb.w;
    v0 = (v0 > 0.f) ? v0 : __expf(v0) - 1.f;   // ELU (bf16-quantized below)
    v1 = (v1 > 0.f) ? v1 : __expf(v1) - 1.f;
    v2 = (v2 > 0.f) ? v2 : __expf(v2) - 1.f;
    v3 = (v3 > 0.f) ? v3 : __expf(v3) - 1.f;
    uint2 w;
    w.x = (unsigned)f2bf(v0) | ((unsigned)f2bf(v1) << 16);
    w.y = (unsigned)f2bf(v2) | ((unsigned)f2bf(v3) << 16);
    *(uint2*)&h2s[local][c8 + strm * 4] = w;
  }
  __syncthreads();

  // ---- Phase B: MFMA [16 x 256] @ [256 x 48] ----
  if (wave < 3) {
    int col = wave * 16 + r16;
    int colc = (col < OUT_C) ? col : 0;
    short8 bfrag[8];
#pragma unroll
    for (int s = 0; s < 8; s++)
      bfrag[s] = *(const short8*)(w2bT + colc * HH + s * 32 + q * 8);
    float sa = 0.f, sd = 0.f, b2c = 0.f;
    if (col < OUT_C) { sa = asrc2[col]; sd = adst2[col]; b2c = b2[col]; }
    floatx4 dacc = {};
#pragma unroll
    for (int s = 0; s < 8; s++) {
      short8 afrag = *(const short8*)&h2s[r16][s * 32 + q * 8];
      dacc = __builtin_amdgcn_mfma_f32_16x16x32_bf16(afrag, bfrag[s], dacc, 0, 0, 0);
    }
    float psr[4], pdr[4];
#pragma unroll
    for (int r = 0; r < 4; r++) {
      float val = dacc[r] + b2c;
      if (col < OUT_C)
        h3[(size_t)(nodeBase + q * 4 + r) * OUT_C + col] = val;
      psr[r] = val * sa;        // sa/sd are 0 for col >= OUT_C
      pdr[r] = val * sd;
    }
#pragma unroll
    for (int o = 8; o > 0; o >>= 1) {
#pragma unroll
      for (int r = 0; r < 4; r++) {
        psr[r] += __shfl_down(psr[r], o, 16);
        pdr[r] += __shfl_down(pdr[r], o, 16);
      }
    }
    if (r16 == 0) {
#pragma unroll
      for (int r = 0; r < 4; r++) {
        psum[wave][q * 4 + r] = psr[r];
        pdsum[wave][q * 4 + r] = pdr[r];
      }
    }
  }
  __syncthreads();
  if (tid < NPB) {
    as2[nodeBase + tid] = psum[0][tid] + psum[1][tid] + psum[2][tid];
    ad2[nodeBase + tid] = pdsum[0][tid] + pdsum[1][tid] + pdsum[2][tid];
  }
}

// ================= L5: agg2 (max-free softmax, dual-stream) + log_softmax ====
__global__ __launch_bounds__(256) void agg2_kernel(
    const float* __restrict__ h3, const float* __restrict__ as2,
    const float* __restrict__ ad2, const int* __restrict__ offs,
    const int* __restrict__ csr, const float* __restrict__ b2,
    float* __restrict__ out) {
  int n = blockIdx.x * 4 + (threadIdx.x >> 6);
  int t = threadIdx.x & 63;
  bool act = (t < OUT_C);
  int beg = offs[n], end = offs[n + 1];
  float ad = ad2[n];
  // two independent accumulation chains for 2x memory-level parallelism
  float l0 = 0.f, l1 = 0.f, a0 = 0.f, a1 = 0.f;
  int k = beg;
  for (; k + 1 < end; k += 2) {
    int s0 = csr[k], s1 = csr[k + 1];
    float e0 = as2[s0] + ad, e1 = as2[s1] + ad;
    e0 = (e0 > 0.f) ? e0 : NEG_SLOPE * e0;
    e1 = (e1 > 0.f) ? e1 : NEG_SLOPE * e1;
    float p0 = __expf(e0), p1 = __expf(e1);
    l0 += p0; l1 += p1;
    float h0 = act ? h3[(size_t)s0 * OUT_C + t] : 0.f;
    float h1 = act ? h3[(size_t)s1 * OUT_C + t] : 0.f;
    a0 = fmaf(p0, h0, a0);
    a1 = fmaf(p1, h1, a1);
  }
  if (k < end) {
    int s0 = csr[k];
    float e0 = as2[s0] + ad;
    e0 = (e0 > 0.f) ? e0 : NEG_SLOPE * e0;
    float p0 = __expf(e0);
    l0 += p0;
    float h0 = act ? h3[(size_t)s0 * OUT_C + t] : 0.f;
    a0 = fmaf(p0, h0, a0);
  }
  float l = l0 + l1, acc = a0 + a1;
  float v = acc / (l + 1e-16f) + (act ? b2[t] : 0.f);
  float x = act ? v : -INFINITY;
  float mx = x;
  for (int o = 32; o > 0; o >>= 1) mx = fmaxf(mx, __shfl_down(mx, o, 64));
  mx = __shfl(mx, 0, 64);
  float ex = act ? __expf(v - mx) : 0.f;
  float s = ex;
  for (int o = 32; o > 0; o >>= 1) s += __shfl_down(s, o, 64);
  s = __shfl(s, 0, 64);
  if (act) out[(size_t)n * OUT_C + t] = v - mx - logf(s);
}

extern "C" void kernel_launch(void* const* d_in, const int* in_sizes, int n_in,
                              void* d_out, int out_size, void* d_ws, size_t ws_size,
                              hipStream_t stream) {
  const float* x     = (const float*)d_in[0];
  const int*   ei    = (const int*)d_in[1];
  const float* w1    = (const float*)d_in[2];
  const float* asrc1 = (const float*)d_in[3];
  const float* adst1 = (const float*)d_in[4];
  const float* b1    = (const float*)d_in[5];
  const float* w2    = (const float*)d_in[6];
  const float* asrc2 = (const float*)d_in[7];
  const float* adst2 = (const float*)d_in[8];
  const float* b2    = (const float*)d_in[9];
  float* out = (float*)d_out;

  // workspace carve-up. All extents keep 16B alignment for int4/float4 ops.
  float* fw = (float*)d_ws;
  float* as1   = fw;  fw += (size_t)N_NODES * HEADS;
  float* ad1   = fw;  fw += (size_t)N_NODES * HEADS;
  float* h3    = fw;  fw += (size_t)N_NODES * OUT_C;
  float* as2   = fw;  fw += N_NODES;
  float* ad2   = fw;  fw += N_NODES;
  unsigned short* h1b  = (unsigned short*)fw;  fw += (size_t)N_NODES * HH / 2;
  unsigned short* wbT  = (unsigned short*)fw;  fw += (size_t)IN_C * HH / 2;
  unsigned short* w2bT = (unsigned short*)fw;  fw += (size_t)HH * OUT_C / 2;
  int* deg    = (int*)fw;
  int* offs   = deg + N_NODES;            // N+1 (+3 pad)
  int* cursor = offs + N_NODES + 4;       // 16B-aligned
  int* csr    = cursor + N_NODES;         // ET

  hipMemsetAsync(deg, 0, N_NODES * sizeof(int), stream);

  prep_kernel<<<WCONV_BLOCKS + W2CONV_BLOCKS + COUNT_BLOCKS, 256, 0, stream>>>(
      w1, w2, ei, wbT, w2bT, deg);
  gemm1_kernel<<<GEMM_BLOCKS + 1, 256, 0, stream>>>(x, wbT, b1, h1b, deg, offs, cursor);
  fill_attn1_kernel<<<FILL_BLOCKS + ATTN1_BLOCKS, 256, 0, stream>>>(
      ei, cursor, csr, h1b, asrc1, adst1, as1, ad1);
  layer1_fused_kernel<<<N_NODES / NPB, 256, 0, stream>>>(
      h1b, as1, ad1, offs, csr, b1, w2bT, b2, asrc2, adst2, h3, as2, ad2);
  agg2_kernel<<<N_NODES / 4, 256, 0, stream>>>(h3, as2, ad2, offs, csr, b2, out);
}

// Round 2
// 208.918 us; speedup vs baseline: 1.1208x; 1.0546x over previous
//
#include <hip/hip_runtime.h>
#include <hip/hip_bf16.h>
#include <math.h>

#define N_NODES 20000
#define N_EDGES 320000
#define ET (N_EDGES + N_NODES)   // with self loops = 340000
#define IN_C 512
#define HEADS 8
#define HID 32
#define HH (HEADS * HID)         // 256
#define OUT_C 40
#define NEG_SLOPE 0.2f

typedef __attribute__((ext_vector_type(8))) short short8;
typedef __attribute__((ext_vector_type(4))) float floatx4;

static __device__ __forceinline__ unsigned short f2bf(float f) {
  __hip_bfloat16 h = __float2bfloat16(f);
  return *(unsigned short*)&h;
}
static __device__ __forceinline__ float bf2f_lo(unsigned int u) {
  return __uint_as_float(u << 16);
}
static __device__ __forceinline__ float bf2f_hi(unsigned int u) {
  return __uint_as_float(u & 0xFFFF0000u);
}

// ================= L1: w1/w2 -> bf16 (w2 transposed)  +  edge count ==========
#define WCONV_BLOCKS (IN_C * HH / 256)          // 512
#define W2CONV_BLOCKS (HH * OUT_C / 256)        // 40
#define COUNT_BLOCKS ((ET + 255) / 256)         // 1329
__global__ __launch_bounds__(256) void prep_kernel(
    const float* __restrict__ w1, const float* __restrict__ w2,
    const int* __restrict__ ei, unsigned short* __restrict__ wbT,
    unsigned short* __restrict__ w2bT, int* __restrict__ deg) {
  if (blockIdx.x < WCONV_BLOCKS) {
    int j = blockIdx.x * 256 + threadIdx.x;     // coalesced read of w1
    int k = j >> 8, n = j & 255;
    wbT[(size_t)n * IN_C + k] = f2bf(w1[j]);
  } else if (blockIdx.x < WCONV_BLOCKS + W2CONV_BLOCKS) {
    int j = (blockIdx.x - WCONV_BLOCKS) * 256 + threadIdx.x;  // 10240
    int k = j / OUT_C, oc = j % OUT_C;
    w2bT[oc * HH + k] = f2bf(w2[j]);
  } else {
    int e = (blockIdx.x - WCONV_BLOCKS - W2CONV_BLOCKS) * 256 + threadIdx.x;
    if (e < ET) {
      int dst = (e < N_EDGES) ? ei[N_EDGES + e] : (e - N_EDGES);
      atomicAdd(&deg[dst], 1);
    }
  }
}

// ================= L2: GEMM1 (MFMA bf16, f32 A staged+converted) + CSR scan ==
#define BM 64
#define BN 128
#define BK 32
#define APAD 40   // row stride in shorts (80B)
#define GY ((N_NODES + BM - 1) / BM)            // 313
#define GEMM_BLOCKS (2 * GY)                    // 626
__global__ __launch_bounds__(256) void gemm1_kernel(
    const float* __restrict__ X, const unsigned short* __restrict__ BT,
    const float* __restrict__ bias, unsigned short* __restrict__ C,
    const int* __restrict__ deg, int* __restrict__ offs, int* __restrict__ cursor) {
  if (blockIdx.x >= GEMM_BLOCKS) {
    // ---- CSR exclusive scan: 250 threads x 80 nodes, register-buffered ----
    __shared__ int wsum[4];
    int t = threadIdx.x;
    int4 buf[20];
    int s = 0;
    if (t < 250) {
      const int4* dp = (const int4*)deg + t * 20;
#pragma unroll
      for (int i = 0; i < 20; i++) {
        buf[i] = dp[i];                      // independent loads — pipelined
        s += buf[i].x + buf[i].y + buf[i].z + buf[i].w;
      }
    }
    int lane = t & 63, w = t >> 6;
    int inc = s;
    for (int o = 1; o < 64; o <<= 1) {
      int u = __shfl_up(inc, o, 64);
      if (lane >= o) inc += u;
    }
    if (lane == 63) wsum[w] = inc;
    __syncthreads();
    int waveOff = 0;
    for (int i = 0; i < w; i++) waveOff += wsum[i];
    int running = waveOff + inc - s;         // exclusive thread offset
    if (t < 250) {
      int base = t * 80;
#pragma unroll
      for (int i = 0; i < 20; i++) {
        int4 v = buf[i];
        int4 o;
        o.x = running;
        o.y = o.x + v.x;
        o.z = o.y + v.y;
        o.w = o.z + v.z;
        running = o.w + v.w;
        *(int4*)(offs + base + i * 4) = o;
        *(int4*)(cursor + base + i * 4) = o;
      }
    }
    if (t == 0) offs[N_NODES] = ET;
    return;
  }
  // ---- GEMM tile ----
  __shared__ unsigned short As[BM][APAD];   // [64][40]
  __shared__ unsigned short Bs[BN][APAD];   // [128][40]
  const int tid = threadIdx.x;
  const int lane = tid & 63, wave = tid >> 6;
  const int wm = (wave & 1) * 32;
  const int wn = (wave >> 1) * 64;
  const int r16 = lane & 15, q = lane >> 4;
  const int bx = blockIdx.x & 1, by = blockIdx.x >> 1;
  const int rowBase = by * BM;
  const int colBase = bx * BN;
  floatx4 acc[2][4] = {};

  for (int k0 = 0; k0 < IN_C; k0 += BK) {
    {
      int row = tid >> 2, kc = (tid & 3) * 8;
      int arow = rowBase + row;
      float4 v0 = make_float4(0.f, 0.f, 0.f, 0.f), v1 = v0;
      if (arow < N_NODES) {
        const float* p = X + (size_t)arow * IN_C + k0 + kc;
        v0 = *(const float4*)p;
        v1 = *(const float4*)(p + 4);
      }
      unsigned short tmp[8] = {f2bf(v0.x), f2bf(v0.y), f2bf(v0.z), f2bf(v0.w),
                               f2bf(v1.x), f2bf(v1.y), f2bf(v1.z), f2bf(v1.w)};
      *(float4*)&As[row][kc] = *(const float4*)tmp;
    }
#pragma unroll
    for (int i = 0; i < 2; i++) {
      int c = tid + i * 256;
      int row = c >> 2, kc = (c & 3) * 8;
      float4 v = *(const float4*)(BT + (size_t)(colBase + row) * IN_C + k0 + kc);
      *(float4*)&Bs[row][kc] = v;
    }
    __syncthreads();
    short8 afrag[2], bfrag[4];
#pragma unroll
    for (int mt = 0; mt < 2; mt++)
      afrag[mt] = *(const short8*)&As[wm + mt * 16 + r16][q * 8];
#pragma unroll
    for (int nt = 0; nt < 4; nt++)
      bfrag[nt] = *(const short8*)&Bs[wn + nt * 16 + r16][q * 8];
#pragma unroll
    for (int mt = 0; mt < 2; mt++)
#pragma unroll
      for (int nt = 0; nt < 4; nt++)
        acc[mt][nt] = __builtin_amdgcn_mfma_f32_16x16x32_bf16(
            afrag[mt], bfrag[nt], acc[mt][nt], 0, 0, 0);
    __syncthreads();
  }
#pragma unroll
  for (int mt = 0; mt < 2; mt++) {
#pragma unroll
    for (int nt = 0; nt < 4; nt++) {
      int col = colBase + wn + nt * 16 + r16;
      float bb = bias[col];
#pragma unroll
      for (int r = 0; r < 4; r++) {
        int row = rowBase + wm + mt * 16 + q * 4 + r;
        if (row < N_NODES) C[(size_t)row * HH + col] = f2bf(acc[mt][nt][r] + bb);
      }
    }
  }
}

// ================= L3: CSR fill + attn1 (wave-per-node dots) =================
#define FILL_BLOCKS ((ET + 255) / 256)          // 1329
#define ATTN1_BLOCKS (N_NODES / 4)              // 5000
__global__ __launch_bounds__(256) void fill_attn1_kernel(
    const int* __restrict__ ei, int* __restrict__ cursor, int* __restrict__ csr,
    const unsigned short* __restrict__ h1b, const float* __restrict__ asrc,
    const float* __restrict__ adst, float* __restrict__ as1, float* __restrict__ ad1) {
  if (blockIdx.x < FILL_BLOCKS) {
    int e = blockIdx.x * 256 + threadIdx.x;
    if (e >= ET) return;
    int src, dst;
    if (e < N_EDGES) { src = ei[e]; dst = ei[N_EDGES + e]; }
    else { src = e - N_EDGES; dst = src; }
    int pos = atomicAdd(&cursor[dst], 1);
    csr[pos] = src;
  } else {
    int wave = threadIdx.x >> 6, lane = threadIdx.x & 63;
    int n = (blockIdx.x - FILL_BLOCKS) * 4 + wave;   // exact: 5000*4 = 20000
    int c4 = lane * 4;
    uint2 raw = *(const uint2*)(h1b + (size_t)n * HH + c4);
    float h0 = bf2f_lo(raw.x), h1 = bf2f_hi(raw.x);
    float h2 = bf2f_lo(raw.y), h3 = bf2f_hi(raw.y);
    float4 sa = *(const float4*)(asrc + c4);
    float4 sd = *(const float4*)(adst + c4);
    float ps = h0 * sa.x + h1 * sa.y + h2 * sa.z + h3 * sa.w;
    float pd = h0 * sd.x + h1 * sd.y + h2 * sd.z + h3 * sd.w;
#pragma unroll
    for (int o = 4; o > 0; o >>= 1) {
      ps += __shfl_down(ps, o, 8);
      pd += __shfl_down(pd, o, 8);
    }
    if ((lane & 7) == 0) {
      as1[n * HEADS + (lane >> 3)] = ps;
      ad1[n * HEADS + (lane >> 3)] = pd;
    }
  }
}

// ================= L4: fused agg1 + GEMM2(MFMA) + attn2 ======================
// Block = 16 nodes, 8 waves (512 thr), 2 nodes per wave. Phase A: per node,
// up to 64 CSR indices are batch-loaded by one coalesced 64-lane read and
// broadcast via shfl -- removes the serial csr->h1b pointer-chase (only the
// h1b row load remains on the critical path, hidden by the 1-deep rotation).
// 2 edge streams x 32 lanes, one contiguous 16B chunk (8 channels) per lane.
// 512-thr blocks + launch_bounds(512,8) double resident waves vs the 256-thr
// version (occupancy was 25%). Phase B (waves 0-2): MFMA [16x256]@[256x48].
#define NPB 16
#define H2ROW 264
__global__ __launch_bounds__(512, 8) void layer1_fused_kernel(
    const unsigned short* __restrict__ h1b, const float* __restrict__ as1,
    const float* __restrict__ ad1, const int* __restrict__ offs,
    const int* __restrict__ csr, const float* __restrict__ b1,
    const unsigned short* __restrict__ w2bT, const float* __restrict__ b2,
    const float* __restrict__ asrc2, const float* __restrict__ adst2,
    float* __restrict__ h3, float* __restrict__ as2, float* __restrict__ ad2) {
  __shared__ __align__(16) unsigned short h2s[NPB][H2ROW];  // 8448 B
  __shared__ float psum[3][NPB], pdsum[3][NPB];
  const int tid = threadIdx.x;
  const int wave = tid >> 6, lane = tid & 63;
  const int r16 = lane & 15, q = lane >> 4;
  const int nodeBase = blockIdx.x * NPB;

  // ---- Phase A: gather, 2 streams x 32 lanes, 8 contiguous channels/lane ----
  const int strm = lane >> 5;          // 0..1: edge stream
  const int l32 = lane & 31;
  const int c8 = l32 * 8;              // channel base (16 B)
  const int head = l32 >> 2;           // 8 channels sit inside one 32-ch head
  float4 bb = *(const float4*)(b1 + c8 + strm * 4);   // this lane's 4 out chans
#pragma unroll
  for (int i = 0; i < 2; i++) {
    int local = wave * 2 + i;
    int n = nodeBase + local;
    int beg = offs[n], end = offs[n + 1];
    int cnt = end - beg;
    float ad = ad1[n * HEADS + head];
    float acc[8] = {};
    float l = 0.f;
    for (int kb = 0; kb < cnt; kb += 64) {
      int nb = (cnt - kb < 64) ? (cnt - kb) : 64;
      // one coalesced load grabs this batch of edge indices for the node
      int myidx = (lane < nb) ? csr[beg + kb + lane] : 0;
      int j = strm;
      if (j < nb) {
        int src = __shfl(myidx, j, 64);
        uint4 r = *(const uint4*)(h1b + ((unsigned)src << 8) + c8);
        float e = as1[src * HEADS + head];
        for (j += 2; j < nb; j += 2) {
          int src2 = __shfl(myidx, j, 64);         // VALU-cheap, no load chain
          uint4 r2 = *(const uint4*)(h1b + ((unsigned)src2 << 8) + c8);
          float e2 = as1[src2 * HEADS + head];
          float tt = e + ad;
          tt = (tt > 0.f) ? tt : NEG_SLOPE * tt;
          float p = __expf(tt);
          l += p;
          acc[0] = fmaf(p, bf2f_lo(r.x), acc[0]);
          acc[1] = fmaf(p, bf2f_hi(r.x), acc[1]);
          acc[2] = fmaf(p, bf2f_lo(r.y), acc[2]);
          acc[3] = fmaf(p, bf2f_hi(r.y), acc[3]);
          acc[4] = fmaf(p, bf2f_lo(r.z), acc[4]);
          acc[5] = fmaf(p, bf2f_hi(r.z), acc[5]);
          acc[6] = fmaf(p, bf2f_lo(r.w), acc[6]);
          acc[7] = fmaf(p, bf2f_hi(r.w), acc[7]);
          r = r2; e = e2;
        }
        float tt = e + ad;
        tt = (tt > 0.f) ? tt : NEG_SLOPE * tt;
        float p = __expf(tt);
        l += p;
        acc[0] = fmaf(p, bf2f_lo(r.x), acc[0]);
        acc[1] = fmaf(p, bf2f_hi(r.x), acc[1]);
        acc[2] = fmaf(p, bf2f_lo(r.y), acc[2]);
        acc[3] = fmaf(p, bf2f_hi(r.y), acc[3]);
        acc[4] = fmaf(p, bf2f_lo(r.z), acc[4]);
        acc[5] = fmaf(p, bf2f_hi(r.z), acc[5]);
        acc[6] = fmaf(p, bf2f_lo(r.w), acc[6]);
        acc[7] = fmaf(p, bf2f_hi(r.w), acc[7]);
      }
    }
    // combine the two streams (butterfly -> both halves hold totals)
#pragma unroll
    for (int j = 0; j < 8; j++) acc[j] += __shfl_xor(acc[j], 32, 64);
    l += __shfl_xor(l, 32, 64);
    float li = 1.f / (l + 1e-16f);
    // each half-wave finalizes 4 of this lane's 8 channels
    float v0 = (strm ? acc[4] : acc[0]) * li + bb.x;
    float v1 = (strm ? acc[5] : acc[1]) * li + bb.y;
    float v2 = (strm ? acc[6] : acc[2]) * li + bb.z;
    float v3 = (strm ? acc[7] : acc[3]) * li + bb.w;
    v0 = (v0 > 0.f) ? v0 : __expf(v0) - 1.f;   // ELU (bf16-quantized below)
    v1 = (v1 > 0.f) ? v1 : __expf(v1) - 1.f;
    v2 = (v2 > 0.f) ? v2 : __expf(v2) - 1.f;
    v3 = (v3 > 0.f) ? v3 : __expf(v3) - 1.f;
    uint2 w;
    w.x = (unsigned)f2bf(v0) | ((unsigned)f2bf(v1) << 16);
    w.y = (unsigned)f2bf(v2) | ((unsigned)f2bf(v3) << 16);
    *(uint2*)&h2s[local][c8 + strm * 4] = w;
  }
  __syncthreads();

  // ---- Phase B: MFMA [16 x 256] @ [256 x 48] ----
  if (wave < 3) {
    int col = wave * 16 + r16;
    int colc = (col < OUT_C) ? col : 0;
    short8 bfrag[8];
#pragma unroll
    for (int s = 0; s < 8; s++)
      bfrag[s] = *(const short8*)(w2bT + colc * HH + s * 32 + q * 8);
    float sa = 0.f, sd = 0.f, b2c = 0.f;
    if (col < OUT_C) { sa = asrc2[col]; sd = adst2[col]; b2c = b2[col]; }
    floatx4 dacc = {};
#pragma unroll
    for (int s = 0; s < 8; s++) {
      short8 afrag = *(const short8*)&h2s[r16][s * 32 + q * 8];
      dacc = __builtin_amdgcn_mfma_f32_16x16x32_bf16(afrag, bfrag[s], dacc, 0, 0, 0);
    }
    float psr[4], pdr[4];
#pragma unroll
    for (int r = 0; r < 4; r++) {
      float val = dacc[r] + b2c;
      if (col < OUT_C)
        h3[(size_t)(nodeBase + q * 4 + r) * OUT_C + col] = val;
      psr[r] = val * sa;        // sa/sd are 0 for col >= OUT_C
      pdr[r] = val * sd;
    }
#pragma unroll
    for (int o = 8; o > 0; o >>= 1) {
#pragma unroll
      for (int r = 0; r < 4; r++) {
        psr[r] += __shfl_down(psr[r], o, 16);
        pdr[r] += __shfl_down(pdr[r], o, 16);
      }
    }
    if (r16 == 0) {
#pragma unroll
      for (int r = 0; r < 4; r++) {
        psum[wave][q * 4 + r] = psr[r];
        pdsum[wave][q * 4 + r] = pdr[r];
      }
    }
  }
  __syncthreads();
  if (tid < NPB) {
    as2[nodeBase + tid] = psum[0][tid] + psum[1][tid] + psum[2][tid];
    ad2[nodeBase + tid] = pdsum[0][tid] + pdsum[1][tid] + pdsum[2][tid];
  }
}

// ================= L5: agg2 (max-free softmax, 4-stream) + log_softmax ======
__global__ __launch_bounds__(256) void agg2_kernel(
    const float* __restrict__ h3, const float* __restrict__ as2,
    const float* __restrict__ ad2, const int* __restrict__ offs,
    const int* __restrict__ csr, const float* __restrict__ b2,
    float* __restrict__ out) {
  int n = blockIdx.x * 4 + (threadIdx.x >> 6);
  int t = threadIdx.x & 63;
  bool act = (t < OUT_C);
  int beg = offs[n], end = offs[n + 1];
  float ad = ad2[n];
  // four independent accumulation chains for 4x memory-level parallelism
  float l0 = 0.f, l1 = 0.f, l2 = 0.f, l3 = 0.f;
  float a0 = 0.f, a1 = 0.f, a2 = 0.f, a3 = 0.f;
  int k = beg;
  for (; k + 3 < end; k += 4) {
    int s0 = csr[k], s1 = csr[k + 1], s2 = csr[k + 2], s3 = csr[k + 3];
    float e0 = as2[s0] + ad, e1 = as2[s1] + ad;
    float e2 = as2[s2] + ad, e3 = as2[s3] + ad;
    e0 = (e0 > 0.f) ? e0 : NEG_SLOPE * e0;
    e1 = (e1 > 0.f) ? e1 : NEG_SLOPE * e1;
    e2 = (e2 > 0.f) ? e2 : NEG_SLOPE * e2;
    e3 = (e3 > 0.f) ? e3 : NEG_SLOPE * e3;
    float p0 = __expf(e0), p1 = __expf(e1), p2 = __expf(e2), p3 = __expf(e3);
    l0 += p0; l1 += p1; l2 += p2; l3 += p3;
    float h0 = act ? h3[(size_t)s0 * OUT_C + t] : 0.f;
    float h1 = act ? h3[(size_t)s1 * OUT_C + t] : 0.f;
    float h2 = act ? h3[(size_t)s2 * OUT_C + t] : 0.f;
    float h3v = act ? h3[(size_t)s3 * OUT_C + t] : 0.f;
    a0 = fmaf(p0, h0, a0);
    a1 = fmaf(p1, h1, a1);
    a2 = fmaf(p2, h2, a2);
    a3 = fmaf(p3, h3v, a3);
  }
  for (; k < end; k++) {
    int s0 = csr[k];
    float e0 = as2[s0] + ad;
    e0 = (e0 > 0.f) ? e0 : NEG_SLOPE * e0;
    float p0 = __expf(e0);
    l0 += p0;
    float h0 = act ? h3[(size_t)s0 * OUT_C + t] : 0.f;
    a0 = fmaf(p0, h0, a0);
  }
  float l = (l0 + l1) + (l2 + l3), acc = (a0 + a1) + (a2 + a3);
  float v = acc / (l + 1e-16f) + (act ? b2[t] : 0.f);
  float x = act ? v : -INFINITY;
  float mx = x;
  for (int o = 32; o > 0; o >>= 1) mx = fmaxf(mx, __shfl_down(mx, o, 64));
  mx = __shfl(mx, 0, 64);
  float ex = act ? __expf(v - mx) : 0.f;
  float s = ex;
  for (int o = 32; o > 0; o >>= 1) s += __shfl_down(s, o, 64);
  s = __shfl(s, 0, 64);
  if (act) out[(size_t)n * OUT_C + t] = v - mx - logf(s);
}

extern "C" void kernel_launch(void* const* d_in, const int* in_sizes, int n_in,
                              void* d_out, int out_size, void* d_ws, size_t ws_size,
                              hipStream_t stream) {
  const float* x     = (const float*)d_in[0];
  const int*   ei    = (const int*)d_in[1];
  const float* w1    = (const float*)d_in[2];
  const float* asrc1 = (const float*)d_in[3];
  const float* adst1 = (const float*)d_in[4];
  const float* b1    = (const float*)d_in[5];
  const float* w2    = (const float*)d_in[6];
  const float* asrc2 = (const float*)d_in[7];
  const float* adst2 = (const float*)d_in[8];
  const float* b2    = (const float*)d_in[9];
  float* out = (float*)d_out;

  // workspace carve-up. All extents keep 16B alignment for int4/float4 ops.
  float* fw = (float*)d_ws;
  float* as1   = fw;  fw += (size_t)N_NODES * HEADS;
  float* ad1   = fw;  fw += (size_t)N_NODES * HEADS;
  float* h3    = fw;  fw += (size_t)N_NODES * OUT_C;
  float* as2   = fw;  fw += N_NODES;
  float* ad2   = fw;  fw += N_NODES;
  unsigned short* h1b  = (unsigned short*)fw;  fw += (size_t)N_NODES * HH / 2;
  unsigned short* wbT  = (unsigned short*)fw;  fw += (size_t)IN_C * HH / 2;
  unsigned short* w2bT = (unsigned short*)fw;  fw += (size_t)HH * OUT_C / 2;
  int* deg    = (int*)fw;
  int* offs   = deg + N_NODES;            // N+1 (+3 pad)
  int* cursor = offs + N_NODES + 4;       // 16B-aligned
  int* csr    = cursor + N_NODES;         // ET

  hipMemsetAsync(deg, 0, N_NODES * sizeof(int), stream);

  prep_kernel<<<WCONV_BLOCKS + W2CONV_BLOCKS + COUNT_BLOCKS, 256, 0, stream>>>(
      w1, w2, ei, wbT, w2bT, deg);
  gemm1_kernel<<<GEMM_BLOCKS + 1, 256, 0, stream>>>(x, wbT, b1, h1b, deg, offs, cursor);
  fill_attn1_kernel<<<FILL_BLOCKS + ATTN1_BLOCKS, 256, 0, stream>>>(
      ei, cursor, csr, h1b, asrc1, adst1, as1, ad1);
  layer1_fused_kernel<<<N_NODES / NPB, 512, 0, stream>>>(
      h1b, as1, ad1, offs, csr, b1, w2bT, b2, asrc2, adst2, h3, as2, ad2);
  agg2_kernel<<<N_NODES / 4, 256, 0, stream>>>(h3, as2, ad2, offs, csr, b2, out);
}

// Round 3
// 204.858 us; speedup vs baseline: 1.1430x; 1.0198x over previous
//
#include <hip/hip_runtime.h>
#include <hip/hip_bf16.h>
#include <math.h>

#define N_NODES 20000
#define N_EDGES 320000
#define ET (N_EDGES + N_NODES)   // with self loops = 340000
#define IN_C 512
#define HEADS 8
#define HID 32
#define HH (HEADS * HID)         // 256
#define OUT_C 40
#define NEG_SLOPE 0.2f

typedef __attribute__((ext_vector_type(8))) short short8;
typedef __attribute__((ext_vector_type(4))) float floatx4;

static __device__ __forceinline__ unsigned short f2bf(float f) {
  __hip_bfloat16 h = __float2bfloat16(f);
  return *(unsigned short*)&h;
}
static __device__ __forceinline__ float bf2f_lo(unsigned int u) {
  return __uint_as_float(u << 16);
}
static __device__ __forceinline__ float bf2f_hi(unsigned int u) {
  return __uint_as_float(u & 0xFFFF0000u);
}

// ================= L1: w1/w2 -> bf16 (w2 transposed)  +  edge count ==========
#define WCONV_BLOCKS (IN_C * HH / 256)          // 512
#define W2CONV_BLOCKS (HH * OUT_C / 256)        // 40
#define COUNT_BLOCKS ((ET + 255) / 256)         // 1329
__global__ __launch_bounds__(256) void prep_kernel(
    const float* __restrict__ w1, const float* __restrict__ w2,
    const int* __restrict__ ei, unsigned short* __restrict__ wbT,
    unsigned short* __restrict__ w2bT, int* __restrict__ deg) {
  if (blockIdx.x < WCONV_BLOCKS) {
    int j = blockIdx.x * 256 + threadIdx.x;     // coalesced read of w1
    int k = j >> 8, n = j & 255;
    wbT[(size_t)n * IN_C + k] = f2bf(w1[j]);
  } else if (blockIdx.x < WCONV_BLOCKS + W2CONV_BLOCKS) {
    int j = (blockIdx.x - WCONV_BLOCKS) * 256 + threadIdx.x;  // 10240
    int k = j / OUT_C, oc = j % OUT_C;
    w2bT[oc * HH + k] = f2bf(w2[j]);
  } else {
    int e = (blockIdx.x - WCONV_BLOCKS - W2CONV_BLOCKS) * 256 + threadIdx.x;
    if (e < ET) {
      int dst = (e < N_EDGES) ? ei[N_EDGES + e] : (e - N_EDGES);
      atomicAdd(&deg[dst], 1);
    }
  }
}

// ================= L2: GEMM1 + fused attn1 epilogue + CSR scan ===============
// XCD-pair swizzle: the two column-blocks (bx=0/1) of a row-tile are placed 8
// apart in dispatch order -> same XCD (round-robin) -> the second block's X
// row-tile read hits that XCD's L2 instead of HBM (halves X traffic).
// attn1 (a_s/a_d dots) computed in-register in the epilogue: each wave's
// 64-col strip is exactly 2 complete heads, reduce over 16 col-lanes by shfl.
#define BM 64
#define BN 128
#define BK 32
#define APAD 40   // row stride in shorts (80B)
#define GY ((N_NODES + BM - 1) / BM)            // 313
#define GEMM_BLOCKS (2 * GY)                    // 626
__global__ __launch_bounds__(256) void gemm1_kernel(
    const float* __restrict__ X, const unsigned short* __restrict__ BT,
    const float* __restrict__ bias, const float* __restrict__ asrc,
    const float* __restrict__ adst, unsigned short* __restrict__ C,
    float* __restrict__ as1, float* __restrict__ ad1,
    const int* __restrict__ deg, int* __restrict__ offs, int* __restrict__ cursor) {
  if (blockIdx.x >= GEMM_BLOCKS) {
    // ---- CSR exclusive scan: 250 threads x 80 nodes, register-buffered ----
    __shared__ int wsum[4];
    int t = threadIdx.x;
    int4 buf[20];
    int s = 0;
    if (t < 250) {
      const int4* dp = (const int4*)deg + t * 20;
#pragma unroll
      for (int i = 0; i < 20; i++) {
        buf[i] = dp[i];                      // independent loads — pipelined
        s += buf[i].x + buf[i].y + buf[i].z + buf[i].w;
      }
    }
    int lane = t & 63, w = t >> 6;
    int inc = s;
    for (int o = 1; o < 64; o <<= 1) {
      int u = __shfl_up(inc, o, 64);
      if (lane >= o) inc += u;
    }
    if (lane == 63) wsum[w] = inc;
    __syncthreads();
    int waveOff = 0;
    for (int i = 0; i < w; i++) waveOff += wsum[i];
    int running = waveOff + inc - s;         // exclusive thread offset
    if (t < 250) {
      int base = t * 80;
#pragma unroll
      for (int i = 0; i < 20; i++) {
        int4 v = buf[i];
        int4 o;
        o.x = running;
        o.y = o.x + v.x;
        o.z = o.y + v.y;
        o.w = o.z + v.z;
        running = o.w + v.w;
        *(int4*)(offs + base + i * 4) = o;
        *(int4*)(cursor + base + i * 4) = o;
      }
    }
    if (t == 0) offs[N_NODES] = ET;
    return;
  }
  // ---- swizzled block id -> (by, bx) with pair on same XCD ----
  int d = blockIdx.x;
  int by, bx;
  const int FULL = (GY / 8) * 16;             // 624
  if (d < FULL) {
    int c = d >> 4, j = d & 15;
    by = c * 8 + (j & 7);
    bx = j >> 3;
  } else {
    int dd = d - FULL;                         // 0..1 (GY%8 == 1)
    by = (GY / 8) * 8 + (dd & 0);              // 312
    bx = dd;
  }
  // ---- GEMM tile ----
  __shared__ unsigned short As[BM][APAD];   // [64][40]
  __shared__ unsigned short Bs[BN][APAD];   // [128][40]
  const int tid = threadIdx.x;
  const int lane = tid & 63, wave = tid >> 6;
  const int wm = (wave & 1) * 32;
  const int wn = (wave >> 1) * 64;
  const int r16 = lane & 15, q = lane >> 4;
  const int rowBase = by * BM;
  const int colBase = bx * BN;
  floatx4 acc[2][4] = {};

  for (int k0 = 0; k0 < IN_C; k0 += BK) {
    {
      int row = tid >> 2, kc = (tid & 3) * 8;
      int arow = rowBase + row;
      float4 v0 = make_float4(0.f, 0.f, 0.f, 0.f), v1 = v0;
      if (arow < N_NODES) {
        const float* p = X + (size_t)arow * IN_C + k0 + kc;
        v0 = *(const float4*)p;
        v1 = *(const float4*)(p + 4);
      }
      unsigned short tmp[8] = {f2bf(v0.x), f2bf(v0.y), f2bf(v0.z), f2bf(v0.w),
                               f2bf(v1.x), f2bf(v1.y), f2bf(v1.z), f2bf(v1.w)};
      *(float4*)&As[row][kc] = *(const float4*)tmp;
    }
#pragma unroll
    for (int i = 0; i < 2; i++) {
      int c = tid + i * 256;
      int row = c >> 2, kc = (c & 3) * 8;
      float4 v = *(const float4*)(BT + (size_t)(colBase + row) * IN_C + k0 + kc);
      *(float4*)&Bs[row][kc] = v;
    }
    __syncthreads();
    short8 afrag[2], bfrag[4];
#pragma unroll
    for (int mt = 0; mt < 2; mt++)
      afrag[mt] = *(const short8*)&As[wm + mt * 16 + r16][q * 8];
#pragma unroll
    for (int nt = 0; nt < 4; nt++)
      bfrag[nt] = *(const short8*)&Bs[wn + nt * 16 + r16][q * 8];
#pragma unroll
    for (int mt = 0; mt < 2; mt++)
#pragma unroll
      for (int nt = 0; nt < 4; nt++)
        acc[mt][nt] = __builtin_amdgcn_mfma_f32_16x16x32_bf16(
            afrag[mt], bfrag[nt], acc[mt][nt], 0, 0, 0);
    __syncthreads();
  }
  // ---- epilogue: store C(+bias) and fused attn1 head dots ----
  float sa[4], sd[4], bbv[4];
#pragma unroll
  for (int nt = 0; nt < 4; nt++) {
    int col = colBase + wn + nt * 16 + r16;
    sa[nt] = asrc[col];
    sd[nt] = adst[col];
    bbv[nt] = bias[col];
  }
  const int headBase = (colBase + wn) >> 5;   // 2 full heads per wave strip
#pragma unroll
  for (int mt = 0; mt < 2; mt++) {
#pragma unroll
    for (int nt = 0; nt < 4; nt++) {
      int col = colBase + wn + nt * 16 + r16;
#pragma unroll
      for (int r = 0; r < 4; r++) {
        int row = rowBase + wm + mt * 16 + q * 4 + r;
        if (row < N_NODES) C[(size_t)row * HH + col] = f2bf(acc[mt][nt][r] + bbv[nt]);
      }
    }
#pragma unroll
    for (int h = 0; h < 2; h++) {
#pragma unroll
      for (int r = 0; r < 4; r++) {
        float v0 = acc[mt][2 * h][r] + bbv[2 * h];
        float v1 = acc[mt][2 * h + 1][r] + bbv[2 * h + 1];
        float ps = v0 * sa[2 * h] + v1 * sa[2 * h + 1];
        float pd = v0 * sd[2 * h] + v1 * sd[2 * h + 1];
#pragma unroll
        for (int o = 1; o < 16; o <<= 1) {
          ps += __shfl_xor(ps, o, 64);
          pd += __shfl_xor(pd, o, 64);
        }
        if (r16 == 0) {
          int row = rowBase + wm + mt * 16 + q * 4 + r;
          if (row < N_NODES) {
            as1[row * HEADS + headBase + h] = ps;
            ad1[row * HEADS + headBase + h] = pd;
          }
        }
      }
    }
  }
}

// ================= L3: CSR fill (scatter by cursor) ==========================
#define FILL_BLOCKS ((ET + 255) / 256)          // 1329
__global__ __launch_bounds__(256) void fill_kernel(
    const int* __restrict__ ei, int* __restrict__ cursor, int* __restrict__ csr) {
  int e = blockIdx.x * 256 + threadIdx.x;
  if (e >= ET) return;
  int src, dst;
  if (e < N_EDGES) { src = ei[e]; dst = ei[N_EDGES + e]; }
  else { src = e - N_EDGES; dst = src; }
  int pos = atomicAdd(&cursor[dst], 1);
  csr[pos] = src;
}

// ================= L4: fused agg1 + GEMM2(MFMA) + attn2 ======================
// Block = 16 nodes, 8 waves (512 thr), 2 nodes per wave. Phase A: per node,
// up to 64 CSR indices are batch-loaded by one coalesced 64-lane read and
// broadcast via shfl -- removes the serial csr->h1b pointer-chase (only the
// h1b row load remains on the critical path, hidden by the 1-deep rotation).
// 2 edge streams x 32 lanes, one contiguous 16B chunk (8 channels) per lane.
// Phase B (waves 0-2): MFMA [16x256]@[256x48].
#define NPB 16
#define H2ROW 264
__global__ __launch_bounds__(512, 8) void layer1_fused_kernel(
    const unsigned short* __restrict__ h1b, const float* __restrict__ as1,
    const float* __restrict__ ad1, const int* __restrict__ offs,
    const int* __restrict__ csr, const float* __restrict__ b1,
    const unsigned short* __restrict__ w2bT, const float* __restrict__ b2,
    const float* __restrict__ asrc2, const float* __restrict__ adst2,
    float* __restrict__ h3, float* __restrict__ as2, float* __restrict__ ad2) {
  __shared__ __align__(16) unsigned short h2s[NPB][H2ROW];  // 8448 B
  __shared__ float psum[3][NPB], pdsum[3][NPB];
  const int tid = threadIdx.x;
  const int wave = tid >> 6, lane = tid & 63;
  const int r16 = lane & 15, q = lane >> 4;
  const int nodeBase = blockIdx.x * NPB;

  // ---- Phase A: gather, 2 streams x 32 lanes, 8 contiguous channels/lane ----
  const int strm = lane >> 5;          // 0..1: edge stream
  const int l32 = lane & 31;
  const int c8 = l32 * 8;              // channel base (16 B)
  const int head = l32 >> 2;           // 8 channels sit inside one 32-ch head
  float4 bb = *(const float4*)(b1 + c8 + strm * 4);   // this lane's 4 out chans
#pragma unroll
  for (int i = 0; i < 2; i++) {
    int local = wave * 2 + i;
    int n = nodeBase + local;
    int beg = offs[n], end = offs[n + 1];
    int cnt = end - beg;
    float ad = ad1[n * HEADS + head];
    float acc[8] = {};
    float l = 0.f;
    for (int kb = 0; kb < cnt; kb += 64) {
      int nb = (cnt - kb < 64) ? (cnt - kb) : 64;
      // one coalesced load grabs this batch of edge indices for the node
      int myidx = (lane < nb) ? csr[beg + kb + lane] : 0;
      int j = strm;
      if (j < nb) {
        int src = __shfl(myidx, j, 64);
        uint4 r = *(const uint4*)(h1b + ((unsigned)src << 8) + c8);
        float e = as1[src * HEADS + head];
        for (j += 2; j < nb; j += 2) {
          int src2 = __shfl(myidx, j, 64);         // VALU-cheap, no load chain
          uint4 r2 = *(const uint4*)(h1b + ((unsigned)src2 << 8) + c8);
          float e2 = as1[src2 * HEADS + head];
          float tt = e + ad;
          tt = (tt > 0.f) ? tt : NEG_SLOPE * tt;
          float p = __expf(tt);
          l += p;
          acc[0] = fmaf(p, bf2f_lo(r.x), acc[0]);
          acc[1] = fmaf(p, bf2f_hi(r.x), acc[1]);
          acc[2] = fmaf(p, bf2f_lo(r.y), acc[2]);
          acc[3] = fmaf(p, bf2f_hi(r.y), acc[3]);
          acc[4] = fmaf(p, bf2f_lo(r.z), acc[4]);
          acc[5] = fmaf(p, bf2f_hi(r.z), acc[5]);
          acc[6] = fmaf(p, bf2f_lo(r.w), acc[6]);
          acc[7] = fmaf(p, bf2f_hi(r.w), acc[7]);
          r = r2; e = e2;
        }
        float tt = e + ad;
        tt = (tt > 0.f) ? tt : NEG_SLOPE * tt;
        float p = __expf(tt);
        l += p;
        acc[0] = fmaf(p, bf2f_lo(r.x), acc[0]);
        acc[1] = fmaf(p, bf2f_hi(r.x), acc[1]);
        acc[2] = fmaf(p, bf2f_lo(r.y), acc[2]);
        acc[3] = fmaf(p, bf2f_hi(r.y), acc[3]);
        acc[4] = fmaf(p, bf2f_lo(r.z), acc[4]);
        acc[5] = fmaf(p, bf2f_hi(r.z), acc[5]);
        acc[6] = fmaf(p, bf2f_lo(r.w), acc[6]);
        acc[7] = fmaf(p, bf2f_hi(r.w), acc[7]);
      }
    }
    // combine the two streams (butterfly -> both halves hold totals)
#pragma unroll
    for (int j = 0; j < 8; j++) acc[j] += __shfl_xor(acc[j], 32, 64);
    l += __shfl_xor(l, 32, 64);
    float li = 1.f / (l + 1e-16f);
    // each half-wave finalizes 4 of this lane's 8 channels
    float v0 = (strm ? acc[4] : acc[0]) * li + bb.x;
    float v1 = (strm ? acc[5] : acc[1]) * li + bb.y;
    float v2 = (strm ? acc[6] : acc[2]) * li + bb.z;
    float v3 = (strm ? acc[7] : acc[3]) * li + bb.w;
    v0 = (v0 > 0.f) ? v0 : __expf(v0) - 1.f;   // ELU (bf16-quantized below)
    v1 = (v1 > 0.f) ? v1 : __expf(v1) - 1.f;
    v2 = (v2 > 0.f) ? v2 : __expf(v2) - 1.f;
    v3 = (v3 > 0.f) ? v3 : __expf(v3) - 1.f;
    uint2 w;
    w.x = (unsigned)f2bf(v0) | ((unsigned)f2bf(v1) << 16);
    w.y = (unsigned)f2bf(v2) | ((unsigned)f2bf(v3) << 16);
    *(uint2*)&h2s[local][c8 + strm * 4] = w;
  }
  __syncthreads();

  // ---- Phase B: MFMA [16 x 256] @ [256 x 48] ----
  if (wave < 3) {
    int col = wave * 16 + r16;
    int colc = (col < OUT_C) ? col : 0;
    short8 bfrag[8];
#pragma unroll
    for (int s = 0; s < 8; s++)
      bfrag[s] = *(const short8*)(w2bT + colc * HH + s * 32 + q * 8);
    float sa = 0.f, sd = 0.f, b2c = 0.f;
    if (col < OUT_C) { sa = asrc2[col]; sd = adst2[col]; b2c = b2[col]; }
    floatx4 dacc = {};
#pragma unroll
    for (int s = 0; s < 8; s++) {
      short8 afrag = *(const short8*)&h2s[r16][s * 32 + q * 8];
      dacc = __builtin_amdgcn_mfma_f32_16x16x32_bf16(afrag, bfrag[s], dacc, 0, 0, 0);
    }
    float psr[4], pdr[4];
#pragma unroll
    for (int r = 0; r < 4; r++) {
      float val = dacc[r] + b2c;
      if (col < OUT_C)
        h3[(size_t)(nodeBase + q * 4 + r) * OUT_C + col] = val;
      psr[r] = val * sa;        // sa/sd are 0 for col >= OUT_C
      pdr[r] = val * sd;
    }
#pragma unroll
    for (int o = 8; o > 0; o >>= 1) {
#pragma unroll
      for (int r = 0; r < 4; r++) {
        psr[r] += __shfl_down(psr[r], o, 16);
        pdr[r] += __shfl_down(pdr[r], o, 16);
      }
    }
    if (r16 == 0) {
#pragma unroll
      for (int r = 0; r < 4; r++) {
        psum[wave][q * 4 + r] = psr[r];
        pdsum[wave][q * 4 + r] = pdr[r];
      }
    }
  }
  __syncthreads();
  if (tid < NPB) {
    as2[nodeBase + tid] = psum[0][tid] + psum[1][tid] + psum[2][tid];
    ad2[nodeBase + tid] = pdsum[0][tid] + pdsum[1][tid] + pdsum[2][tid];
  }
}

// ================= L5: agg2 — lane-parallel edge prep + 4-chain h3 gather ====
// Per 64-edge batch: lane j loads csr and as2, computes p_j = exp(leaky(.))
// in parallel; l accumulated by one wave reduction. The per-edge loop then
// only shfl-broadcasts (src, p) and loads the h3 row — a 1-load critical
// path with 4 independent chains (was csr->as2->h3 serial).
__global__ __launch_bounds__(256) void agg2_kernel(
    const float* __restrict__ h3, const float* __restrict__ as2,
    const float* __restrict__ ad2, const int* __restrict__ offs,
    const int* __restrict__ csr, const float* __restrict__ b2,
    float* __restrict__ out) {
  int n = blockIdx.x * 4 + (threadIdx.x >> 6);
  int t = threadIdx.x & 63;
  bool act = (t < OUT_C);
  int beg = offs[n], end = offs[n + 1];
  int cnt = end - beg;
  float ad = ad2[n];
  float l = 0.f;
  float a0 = 0.f, a1 = 0.f, a2 = 0.f, a3 = 0.f;
  for (int kb = 0; kb < cnt; kb += 64) {
    int nb = (cnt - kb < 64) ? (cnt - kb) : 64;
    int sj = 0;
    float pj = 0.f;
    if (t < nb) {
      sj = csr[beg + kb + t];
      float e = as2[sj] + ad;
      e = (e > 0.f) ? e : NEG_SLOPE * e;
      pj = __expf(e);
    }
    float ll = pj;
#pragma unroll
    for (int o = 32; o > 0; o >>= 1) ll += __shfl_xor(ll, o, 64);
    l += ll;
    int j = 0;
    for (; j + 3 < nb; j += 4) {
      int s0 = __shfl(sj, j, 64), s1 = __shfl(sj, j + 1, 64);
      int s2 = __shfl(sj, j + 2, 64), s3 = __shfl(sj, j + 3, 64);
      float p0 = __shfl(pj, j, 64), p1 = __shfl(pj, j + 1, 64);
      float p2 = __shfl(pj, j + 2, 64), p3 = __shfl(pj, j + 3, 64);
      float h0 = act ? h3[(size_t)s0 * OUT_C + t] : 0.f;
      float h1 = act ? h3[(size_t)s1 * OUT_C + t] : 0.f;
      float h2 = act ? h3[(size_t)s2 * OUT_C + t] : 0.f;
      float h3v = act ? h3[(size_t)s3 * OUT_C + t] : 0.f;
      a0 = fmaf(p0, h0, a0);
      a1 = fmaf(p1, h1, a1);
      a2 = fmaf(p2, h2, a2);
      a3 = fmaf(p3, h3v, a3);
    }
    for (; j < nb; j++) {
      int s0 = __shfl(sj, j, 64);
      float p0 = __shfl(pj, j, 64);
      float h0 = act ? h3[(size_t)s0 * OUT_C + t] : 0.f;
      a0 = fmaf(p0, h0, a0);
    }
  }
  float acc = (a0 + a1) + (a2 + a3);
  float v = acc / (l + 1e-16f) + (act ? b2[t] : 0.f);
  float x = act ? v : -INFINITY;
  float mx = x;
  for (int o = 32; o > 0; o >>= 1) mx = fmaxf(mx, __shfl_down(mx, o, 64));
  mx = __shfl(mx, 0, 64);
  float ex = act ? __expf(v - mx) : 0.f;
  float s = ex;
  for (int o = 32; o > 0; o >>= 1) s += __shfl_down(s, o, 64);
  s = __shfl(s, 0, 64);
  if (act) out[(size_t)n * OUT_C + t] = v - mx - logf(s);
}

extern "C" void kernel_launch(void* const* d_in, const int* in_sizes, int n_in,
                              void* d_out, int out_size, void* d_ws, size_t ws_size,
                              hipStream_t stream) {
  const float* x     = (const float*)d_in[0];
  const int*   ei    = (const int*)d_in[1];
  const float* w1    = (const float*)d_in[2];
  const float* asrc1 = (const float*)d_in[3];
  const float* adst1 = (const float*)d_in[4];
  const float* b1    = (const float*)d_in[5];
  const float* w2    = (const float*)d_in[6];
  const float* asrc2 = (const float*)d_in[7];
  const float* adst2 = (const float*)d_in[8];
  const float* b2    = (const float*)d_in[9];
  float* out = (float*)d_out;

  // workspace carve-up. All extents keep 16B alignment for int4/float4 ops.
  float* fw = (float*)d_ws;
  float* as1   = fw;  fw += (size_t)N_NODES * HEADS;
  float* ad1   = fw;  fw += (size_t)N_NODES * HEADS;
  float* h3    = fw;  fw += (size_t)N_NODES * OUT_C;
  float* as2   = fw;  fw += N_NODES;
  float* ad2   = fw;  fw += N_NODES;
  unsigned short* h1b  = (unsigned short*)fw;  fw += (size_t)N_NODES * HH / 2;
  unsigned short* wbT  = (unsigned short*)fw;  fw += (size_t)IN_C * HH / 2;
  unsigned short* w2bT = (unsigned short*)fw;  fw += (size_t)HH * OUT_C / 2;
  int* deg    = (int*)fw;
  int* offs   = deg + N_NODES;            // N+1 (+3 pad)
  int* cursor = offs + N_NODES + 4;       // 16B-aligned
  int* csr    = cursor + N_NODES;         // ET

  hipMemsetAsync(deg, 0, N_NODES * sizeof(int), stream);

  prep_kernel<<<WCONV_BLOCKS + W2CONV_BLOCKS + COUNT_BLOCKS, 256, 0, stream>>>(
      w1, w2, ei, wbT, w2bT, deg);
  gemm1_kernel<<<GEMM_BLOCKS + 1, 256, 0, stream>>>(
      x, wbT, b1, asrc1, adst1, h1b, as1, ad1, deg, offs, cursor);
  fill_kernel<<<FILL_BLOCKS, 256, 0, stream>>>(ei, cursor, csr);
  layer1_fused_kernel<<<N_NODES / NPB, 512, 0, stream>>>(
      h1b, as1, ad1, offs, csr, b1, w2bT, b2, asrc2, adst2, h3, as2, ad2);
  agg2_kernel<<<N_NODES / 4, 256, 0, stream>>>(h3, as2, ad2, offs, csr, b2, out);
}